// Round 1
// baseline (85.596 us; speedup 1.0000x reference)
//
#include <hip/hip_runtime.h>
#include <hip/hip_fp16.h>

// MinEuclideanDistBlock: out[b,n] = min_w sum_c sqrt(max(||win||^2 + ||shp||^2 - 2*cross, 0))
// B=64, C=3, L=2048, N=256, S=64, W=1985.
// v2: 1024 threads / 16 waves (8 w-groups x 2 n-halves), wave tile 32w x 32n.
//     bfr register file 96->48 VGPRs -> 4 waves/SIMD (was 2).
//     A staged as -2*x in bf16 -> cross term lands pre-scaled; (wsq+ssq) folded into
//     MFMA accumulator init; epilogue = max/sqrt/add only.
//     Rolling win_sq (low register peak), chunked b64 staging writes, hoisted x loads.

typedef float  v4f __attribute__((ext_vector_type(4)));
typedef short  v8s __attribute__((ext_vector_type(8)));
typedef unsigned short u16;
typedef unsigned int   u32;
typedef unsigned long long u64;

#define S_ 64
#define N_ 256
#define C_ 3
#define B_ 64
#define L_ 2048
#define W_ 1985
#define NCHUNK 530   // 8B chunks per shifted copy
#define THREADS 1024
#define WAVES 16

__device__ __forceinline__ u16 f2bf(float f) {
    u32 u = __builtin_bit_cast(u32, f);
    return (u16)((u + 0x7FFFu + ((u >> 16) & 1u)) >> 16);
}
__device__ __forceinline__ float bf2f(u16 b) {
    return __builtin_bit_cast(float, ((u32)b) << 16);
}

__global__ __launch_bounds__(THREADS)
void shapelet_min_kernel(const float* __restrict__ x,
                         const float* __restrict__ shp,
                         float* __restrict__ out)
{
    __shared__ u64 xcopy[C_][4][NCHUNK];     // 50880 B: 4 shifted bf16 copies of -2*x[b,c,:]
    __shared__ __half wsq[C_][L_];           // 12288 B: sliding window sq-norms; aliased as red buf

    const int tid  = threadIdx.x;
    const int wave = tid >> 6;
    const int lane = tid & 63;
    const int m    = lane & 15;      // MFMA row/col within 16
    const int q    = lane >> 4;      // quad id 0..3
    const int ww   = wave >> 1;      // w-group 0..7 (32 windows each per iter)
    const int wn   = wave & 1;       // n-half 0..1 (32 shapelets each)
    const int b    = blockIdx.x >> 2;
    const int n0   = (blockIdx.x & 3) << 6;

    //=== Phase A: stage this block's shapelet tile (bf16) into scratch (aliases xcopy) ===
    u16* scratch = (u16*)&xcopy[0][0][0];    // [C_][64][72] u16 (72 = 64 + pad8)
    #pragma unroll
    for (int k = 0; k < 3; ++k) {
        int idx = tid + k * THREADS;         // 3072 float4-groups: (c, n, sq)
        int sq = idx & 15;
        int n  = (idx >> 4) & 63;
        int c  = idx >> 10;
        v4f v = *(const v4f*)(shp + ((size_t)(c * N_ + n0 + n) * S_ + (sq << 2)));
        u64 pk = (u64)f2bf(v[0]) | ((u64)f2bf(v[1]) << 16)
               | ((u64)f2bf(v[2]) << 32) | ((u64)f2bf(v[3]) << 48);
        *(u64*)(scratch + ((c * 64 + n) * 72 + (sq << 2))) = pk;
    }
    __syncthreads();

    //=== Hoisted x global loads (latency hidden under B-fragment/ssq VALU below) ===
    const float* xb = x + (size_t)b * (C_ * L_);
    float xf[2][8];
    int xc[2], xt[2];
    #pragma unroll
    for (int k = 0; k < 2; ++k) {
        int u = tid + k * THREADS;
        bool act = (u < C_ * NCHUNK);        // 1590 chunk-units
        int uu = act ? u : 0;
        int c = uu / NCHUNK;
        int t = uu - c * NCHUNK;
        int e = t << 2;
        xc[k] = c; xt[k] = t;
        if (act && (e + 7 < L_)) {
            v4f a0 = *(const v4f*)(xb + c * L_ + e);
            v4f a1 = *(const v4f*)(xb + c * L_ + e + 4);
            xf[k][0] = a0[0]; xf[k][1] = a0[1]; xf[k][2] = a0[2]; xf[k][3] = a0[3];
            xf[k][4] = a1[0]; xf[k][5] = a1[1]; xf[k][6] = a1[2]; xf[k][7] = a1[3];
        } else {
            #pragma unroll
            for (int i = 0; i < 8; ++i)
                xf[k][i] = (act && (e + i < L_)) ? xb[c * L_ + e + i] : 0.f;
        }
    }

    //=== B fragments -> registers (48 VGPRs) + shapelet norms per lane's n ===
    v8s bfr[C_][2][2];
    float ssq[C_][2];
    #pragma unroll
    for (int c = 0; c < C_; ++c) {
        #pragma unroll
        for (int nt = 0; nt < 2; ++nt) {
            float sacc = 0.f;
            #pragma unroll
            for (int h = 0; h < 2; ++h) {
                v8s f = *(const v8s*)(scratch +
                         ((c * 64 + wn * 32 + nt * 16 + m) * 72 + h * 32 + q * 8));
                bfr[c][nt][h] = f;
                #pragma unroll
                for (int j = 0; j < 8; ++j) {
                    float e = bf2f((u16)f[j]);
                    sacc += e * e;
                }
            }
            sacc += __shfl_xor(sacc, 16);
            sacc += __shfl_xor(sacc, 32);
            ssq[c][nt] = sacc;               // per-lane n = wn*32 + nt*16 + m
        }
    }
    __syncthreads();

    //=== Phase B: write 4 shifted bf16 copies of -2*x[b] as whole aligned chunks ===
    #pragma unroll
    for (int k = 0; k < 2; ++k) {
        int u = tid + k * THREADS;
        if (u < C_ * NCHUNK) {
            u16 w8[8];
            #pragma unroll
            for (int i = 0; i < 8; ++i) w8[i] = f2bf(-2.f * xf[k][i]);
            #pragma unroll
            for (int r = 0; r < 4; ++r) {    // copy r chunk t = elements 4t+r .. 4t+r+3
                u64 pk = (u64)w8[r] | ((u64)w8[r + 1] << 16)
                       | ((u64)w8[r + 2] << 32) | ((u64)w8[r + 3] << 48);
                xcopy[xc[k]][r][xt[k]] = pk;
            }
        }
    }
    __syncthreads();

    //=== win_sq: rolling sliding sum of squares from copy 0 (values are -2x -> *0.25) ===
    #pragma unroll
    for (int k = 0; k < 2; ++k) {
        int u = tid + k * THREADS;           // 1536 units: (c, 4-window group)
        if (u < 512 * C_) {
            int c  = u >> 9;
            int t0 = u & 511;                // window base = 4*t0
            const u64* cp0 = &xcopy[c][0][0];
            u64 ch = cp0[t0];
            float h0 = bf2f((u16)ch),         h1 = bf2f((u16)(ch >> 16)),
                  h2 = bf2f((u16)(ch >> 32)), h3 = bf2f((u16)(ch >> 48));
            float s = h0 * h0 + h1 * h1 + h2 * h2 + h3 * h3;
            #pragma unroll
            for (int kk = 1; kk < 16; ++kk) {
                u64 c2 = cp0[t0 + kk];
                float e0 = bf2f((u16)c2),         e1 = bf2f((u16)(c2 >> 16)),
                      e2 = bf2f((u16)(c2 >> 32)), e3 = bf2f((u16)(c2 >> 48));
                s += e0 * e0; s += e1 * e1; s += e2 * e2; s += e3 * e3;
            }
            u64 ct = cp0[t0 + 16];
            float t4 = bf2f((u16)ct), t5 = bf2f((u16)(ct >> 16)), t6 = bf2f((u16)(ct >> 32));
            float s0 = s;
            float s1 = s0 - h0 * h0 + t4 * t4;
            float s2 = s1 - h1 * h1 + t5 * t5;
            float s3 = s2 - h2 * h2 + t6 * t6;
            union { u64 u; __half h[4]; } hp;
            hp.h[0] = __float2half(0.25f * s0); hp.h[1] = __float2half(0.25f * s1);
            hp.h[2] = __float2half(0.25f * s2); hp.h[3] = __float2half(0.25f * s3);
            *(u64*)&wsq[c][t0 << 2] = hp.u;
        }
    }
    __syncthreads();

    //=== Main loop: 8 iters x (wave tile 32w x 32n), channels fused before min ===
    float mins[2] = {1e30f, 1e30f};
    const int r = m & 3;

    #pragma unroll 1
    for (int it = 0; it < 8; ++it) {
        const int wbase = it * 256 + ww * 32;
        if (wbase >= W_) continue;           // only ww=7 @ it7 fully invalid

        float sums[2][2][4];
        #pragma unroll
        for (int mt = 0; mt < 2; ++mt)
            #pragma unroll
            for (int nt = 0; nt < 2; ++nt)
                #pragma unroll
                for (int g = 0; g < 4; ++g) sums[mt][nt][g] = 0.f;

        #pragma unroll
        for (int c = 0; c < C_; ++c) {
            // A-fragments (already -2-scaled): two aligned b64 from copy (m&3)
            v8s afr[2][2];
            #pragma unroll
            for (int mt = 0; mt < 2; ++mt) {
                #pragma unroll
                for (int h = 0; h < 2; ++h) {
                    int p0 = wbase + mt * 16 + m + h * 32 + q * 8;
                    int T  = (p0 - r) >> 2;
                    const u64* cp = &xcopy[c][r][0];
                    union { u64 u[2]; v8s v; } tmp;
                    tmp.u[0] = cp[T];
                    tmp.u[1] = cp[T + 1];
                    afr[mt][h] = tmp.v;
                }
            }
            // accumulator init = wsq(w) + ssq(n); MFMA adds -2*cross on top
            v4f acc[2][2];
            #pragma unroll
            for (int mt = 0; mt < 2; ++mt) {
                union { u64 u; __half h4[4]; } wq;
                wq.u = *(const u64*)&wsq[c][wbase + mt * 16 + q * 4];
                float wv[4];
                #pragma unroll
                for (int g = 0; g < 4; ++g) wv[g] = __half2float(wq.h4[g]);
                #pragma unroll
                for (int nt = 0; nt < 2; ++nt)
                    #pragma unroll
                    for (int g = 0; g < 4; ++g)
                        acc[mt][nt][g] = wv[g] + ssq[c][nt];
            }
            #pragma unroll
            for (int h = 0; h < 2; ++h)
                #pragma unroll
                for (int mt = 0; mt < 2; ++mt)
                    #pragma unroll
                    for (int nt = 0; nt < 2; ++nt)
                        acc[mt][nt] = __builtin_amdgcn_mfma_f32_16x16x32_bf16(
                            afr[mt][h], bfr[c][nt][h], acc[mt][nt], 0, 0, 0);

            // epilogue: d = sqrt(max(d2, 0)); accumulate over channels
            #pragma unroll
            for (int mt = 0; mt < 2; ++mt)
                #pragma unroll
                for (int nt = 0; nt < 2; ++nt)
                    #pragma unroll
                    for (int g = 0; g < 4; ++g)
                        sums[mt][nt][g] += __builtin_amdgcn_sqrtf(fmaxf(acc[mt][nt][g], 0.f));
        }

        // fold into running min over w (mask only needed on the final partial tile)
        if (wbase + 31 < W_) {
            #pragma unroll
            for (int mt = 0; mt < 2; ++mt)
                #pragma unroll
                for (int nt = 0; nt < 2; ++nt)
                    #pragma unroll
                    for (int g = 0; g < 4; ++g)
                        mins[nt] = fminf(mins[nt], sums[mt][nt][g]);
        } else {
            #pragma unroll
            for (int mt = 0; mt < 2; ++mt)
                #pragma unroll
                for (int g = 0; g < 4; ++g) {
                    int w = wbase + mt * 16 + q * 4 + g;
                    bool ok = (w < W_);
                    #pragma unroll
                    for (int nt = 0; nt < 2; ++nt)
                        mins[nt] = fminf(mins[nt], ok ? sums[mt][nt][g] : 1e30f);
                }
        }
    }

    //=== Reductions: across quads (same n, different w-rows), then across waves ===
    #pragma unroll
    for (int nt = 0; nt < 2; ++nt) {
        mins[nt] = fminf(mins[nt], __shfl_xor(mins[nt], 16));
        mins[nt] = fminf(mins[nt], __shfl_xor(mins[nt], 32));
    }
    __syncthreads();                          // all wsq reads done -> safe to alias
    float* red = (float*)&wsq[0][0];          // [8][64]: row = ww, col = local n
    if (lane < 16) {
        red[ww * 64 + wn * 32 + lane]      = mins[0];
        red[ww * 64 + wn * 32 + 16 + lane] = mins[1];
    }
    __syncthreads();
    if (tid < 64) {
        float v = red[tid];
        #pragma unroll
        for (int k = 1; k < 8; ++k) v = fminf(v, red[k * 64 + tid]);
        out[(size_t)b * N_ + n0 + tid] = v;
    }
}

extern "C" void kernel_launch(void* const* d_in, const int* in_sizes, int n_in,
                              void* d_out, int out_size, void* d_ws, size_t ws_size,
                              hipStream_t stream) {
    const float* x   = (const float*)d_in[0];   // (64, 3, 2048) fp32
    const float* shp = (const float*)d_in[1];   // (3, 256, 64) fp32
    float* out       = (float*)d_out;           // (64, 1, 256) fp32
    hipLaunchKernelGGL(shapelet_min_kernel, dim3(256), dim3(THREADS), 0, stream,
                       x, shp, out);
}